// Round 2
// baseline (564.232 us; speedup 1.0000x reference)
//
#include <hip/hip_runtime.h>
#include <math.h>

#define NPTS 65536
#define NSAMP 16
#define CH 64
#define NROWS (NPTS*NSAMP)
#define BN_EPS 1e-5f

// workspace layout (float offsets)
#define OFF_S3   0            // sum3[3], sq3[3]
#define OFF_F3   8            // scale3[3], shift3[3]
#define OFF_S64  16           // sum64[64] @16, sq64[64] @80
#define OFF_F64  144          // scale64[64] @144, shift64[64] @208
#define OFF_S8   272          // sum8[8], sq8[8]
#define OFF_F8   288          // scale8[8], shift8[8]
#define OFF_XQ   512
#define OFF_XK   (OFF_XQ + NPTS*CH)
#define OFF_XV   (OFF_XK + NPTS*CH)
#define OFF_PR1  (OFF_XV + NPTS*CH)
#define OFF_W2   (OFF_PR1 + NROWS*3)

__device__ __forceinline__ float wave_sum(float v){
#pragma unroll
  for (int m = 32; m > 0; m >>= 1) v += __shfl_xor(v, m);
  return v;
}

__global__ void k_zero(float* __restrict__ ws){
  if (threadIdx.x < 512) ws[threadIdx.x] = 0.0f;
}

// q/k/v projections: one thread per point, one weight matrix per blockIdx.y
__global__ __launch_bounds__(256) void k_proj(const float* __restrict__ x,
    const float* __restrict__ W0, const float* __restrict__ b0,
    const float* __restrict__ W1, const float* __restrict__ b1,
    const float* __restrict__ W2, const float* __restrict__ b2,
    float* __restrict__ ws)
{
  int n = blockIdx.x * blockDim.x + threadIdx.x;
  const float* W; const float* b; float* out;
  if (blockIdx.y == 0)      { W = W0; b = b0; out = ws + OFF_XQ; }
  else if (blockIdx.y == 1) { W = W1; b = b1; out = ws + OFF_XK; }
  else                      { W = W2; b = b2; out = ws + OFF_XV; }

  float4 xr[16];
  const float4* xp = (const float4*)(x + (size_t)n * CH);
#pragma unroll
  for (int i = 0; i < 16; i++) xr[i] = xp[i];

  float4* op = (float4*)(out + (size_t)n * CH);
#pragma unroll 1
  for (int o4 = 0; o4 < 16; o4++){
    float a[4];
#pragma unroll
    for (int oo = 0; oo < 4; oo++){
      int o = o4 * 4 + oo;
      float acc = b[o];
      const float4* wp = (const float4*)(W + o * CH);
#pragma unroll
      for (int i = 0; i < 16; i++){
        float4 w4 = wp[i];
        acc += xr[i].x * w4.x + xr[i].y * w4.y + xr[i].z * w4.z + xr[i].w * w4.w;
      }
      a[oo] = acc;
    }
    float4 st; st.x = a[0]; st.y = a[1]; st.z = a[2]; st.w = a[3];
    op[o4] = st;
  }
}

// p_r stage 1 (Linear(3,3)) + BN3 partial sums. 4 rows/thread, full ILP.
__global__ __launch_bounds__(256) void k_pr1(const float* __restrict__ p,
    const int* __restrict__ idx, const float* __restrict__ Wp1,
    const float* __restrict__ bp1, float* __restrict__ ws)
{
  float* pr1 = ws + OFF_PR1;
  float w00=Wp1[0],w01=Wp1[1],w02=Wp1[2];
  float w10=Wp1[3],w11=Wp1[4],w12=Wp1[5];
  float w20=Wp1[6],w21=Wp1[7],w22=Wp1[8];
  float b0=bp1[0],b1=bp1[1],b2=bp1[2];
  float s0=0,s1=0,s2=0,q0=0,q1=0,q2=0;
  int r0 = blockIdx.x*256 + threadIdx.x;
#pragma unroll
  for (int it = 0; it < 4; it++){
    int r = r0 + it*262144;
    int n = r >> 4;
    int iv = idx[r];
    float dx = p[iv*3+0] - p[n*3+0];
    float dy = p[iv*3+1] - p[n*3+1];
    float dz = p[iv*3+2] - p[n*3+2];
    float v0 = b0 + dx*w00 + dy*w01 + dz*w02;
    float v1 = b1 + dx*w10 + dy*w11 + dz*w12;
    float v2 = b2 + dx*w20 + dy*w21 + dz*w22;
    pr1[(size_t)r*3+0]=v0; pr1[(size_t)r*3+1]=v1; pr1[(size_t)r*3+2]=v2;
    s0+=v0; s1+=v1; s2+=v2;
    q0+=v0*v0; q1+=v1*v1; q2+=v2*v2;
  }
  s0=wave_sum(s0); s1=wave_sum(s1); s2=wave_sum(s2);
  q0=wave_sum(q0); q1=wave_sum(q1); q2=wave_sum(q2);
  __shared__ float lds[4][6];
  int lane = threadIdx.x & 63, wv = threadIdx.x >> 6;
  if (lane == 0){
    lds[wv][0]=s0; lds[wv][1]=s1; lds[wv][2]=s2;
    lds[wv][3]=q0; lds[wv][4]=q1; lds[wv][5]=q2;
  }
  __syncthreads();
  if (threadIdx.x < 6){
    float v = lds[0][threadIdx.x]+lds[1][threadIdx.x]+lds[2][threadIdx.x]+lds[3][threadIdx.x];
    atomicAdd(ws + OFF_S3 + threadIdx.x, v);
  }
}

// BN finalize: scale = g*rsqrt(var+eps), shift = beta - mean*scale
__global__ void k_finalize(const float* __restrict__ sums, float* __restrict__ outf,
                           const float* __restrict__ g, const float* __restrict__ beta, int nch)
{
  int t = threadIdx.x;
  if (t < nch){
    float invM = 1.0f / (float)NROWS;
    float mean = sums[t] * invM;
    float var  = sums[nch + t] * invM - mean * mean;
    float rs   = rsqrtf(var + BN_EPS);
    float sc   = g[t] * rs;
    outf[t] = sc;
    outf[nch + t] = beta[t] - mean * sc;
  }
}

// BN64 stats over w_pre = xk[idx] - xq + p_r2. Wave per 64-row chunk,
// lane = channel. Coalesced preload of idx/pr1; 8 gathers in flight.
__global__ __launch_bounds__(256) void k_stats64(const int* __restrict__ idx,
    const float* __restrict__ xq, const float* __restrict__ xk,
    const float* __restrict__ pr1, const float* __restrict__ f3,
    const float* __restrict__ Wp2, const float* __restrict__ bp2,
    float* __restrict__ s64)
{
  int lane = threadIdx.x & 63, wv = threadIdx.x >> 6;
  int row0 = __builtin_amdgcn_readfirstlane((blockIdx.x*4 + wv) * 64);
  int n0 = row0 >> 4;

  int   iv_l = idx[row0 + lane];
  float a0_l = pr1[(size_t)(row0 + lane)*3 + 0];
  float a1_l = pr1[(size_t)(row0 + lane)*3 + 1];
  float a2_l = pr1[(size_t)(row0 + lane)*3 + 2];

  float sc0=f3[0], sc1=f3[1], sc2=f3[2], sh0=f3[3], sh1=f3[4], sh2=f3[5];
  float wpa = Wp2[lane*3+0], wpb = Wp2[lane*3+1], wpc = Wp2[lane*3+2];
  float bp  = bp2[lane];

  float xqv0 = xq[(size_t)(n0+0)*CH + lane];
  float xqv1 = xq[(size_t)(n0+1)*CH + lane];
  float xqv2 = xq[(size_t)(n0+2)*CH + lane];
  float xqv3 = xq[(size_t)(n0+3)*CH + lane];

  float accs = 0.0f, accq = 0.0f;
#pragma unroll
  for (int g = 0; g < 8; g++){
    float xkv[8];
#pragma unroll
    for (int u = 0; u < 8; u++){
      int iv = __shfl(iv_l, g*8 + u);
      xkv[u] = xk[(size_t)iv*CH + lane];
    }
    float xqv = (g < 2) ? xqv0 : (g < 4) ? xqv1 : (g < 6) ? xqv2 : xqv3;
#pragma unroll
    for (int u = 0; u < 8; u++){
      int r = g*8 + u;
      float a0 = __shfl(a0_l, r), a1 = __shfl(a1_l, r), a2 = __shfl(a2_l, r);
      float rb0 = fmaxf(fmaf(a0, sc0, sh0), 0.0f);
      float rb1 = fmaxf(fmaf(a1, sc1, sh1), 0.0f);
      float rb2 = fmaxf(fmaf(a2, sc2, sh2), 0.0f);
      float pr2v = bp + rb0*wpa + rb1*wpb + rb2*wpc;
      float w = xkv[u] - xqv + pr2v;
      accs += w; accq = fmaf(w, w, accq);
    }
  }
  __shared__ float lds[4][128];
  lds[wv][lane] = accs; lds[wv][64+lane] = accq;
  __syncthreads();
  if (threadIdx.x < 128){
    float v = lds[0][threadIdx.x]+lds[1][threadIdx.x]+lds[2][threadIdx.x]+lds[3][threadIdx.x];
    atomicAdd(s64 + threadIdx.x, v);
  }
}

// w2 = relu(bn64(w_pre)) @ Ww1^T + bw1 + BN8 partial sums.
// Two-phase: A) wave computes rb for 32 rows (lane=channel) -> LDS;
//            B) 2 threads/row read LDS row, 4 outputs each, coalesced store.
// Block does 4 iterations x 128 rows = 512 rows. Grid = NROWS/512 = 2048.
#define W2PAD 68
__global__ __launch_bounds__(256) void k_w2(const int* __restrict__ idx,
    const float* __restrict__ xq, const float* __restrict__ xk,
    const float* __restrict__ pr1, const float* __restrict__ f3,
    const float* __restrict__ f64, const float* __restrict__ Wp2,
    const float* __restrict__ bp2, const float* __restrict__ Ww1,
    const float* __restrict__ bw1, float* __restrict__ w2o,
    float* __restrict__ s8out)
{
  __shared__ __align__(16) float lds[4][32][W2PAD];
  int t = threadIdx.x;
  int lane = t & 63, wv = t >> 6;
  int hf = t & 1, rloc = t >> 1;

  float sc30=f3[0], sc31=f3[1], sc32=f3[2], sh30=f3[3], sh31=f3[4], sh32=f3[5];
  float wpa = Wp2[lane*3+0], wpb = Wp2[lane*3+1], wpc = Wp2[lane*3+2];
  float bp  = bp2[lane];
  float bsc = f64[lane], bsh = f64[64+lane];

  const float* Wr0 = Ww1 + (hf*4+0)*CH;
  const float* Wr1 = Ww1 + (hf*4+1)*CH;
  const float* Wr2 = Ww1 + (hf*4+2)*CH;
  const float* Wr3 = Ww1 + (hf*4+3)*CH;
  float bb0 = bw1[hf*4+0], bb1 = bw1[hf*4+1], bb2 = bw1[hf*4+2], bb3 = bw1[hf*4+3];

  float sB0=0,sB1=0,sB2=0,sB3=0,qB0=0,qB1=0,qB2=0,qB3=0;

  const float* lrow = &lds[rloc>>5][rloc&31][0];

#pragma unroll 1
  for (int it = 0; it < 4; it++){
    int base = blockIdx.x*512 + it*128;
    // ---- phase A: wave computes rb for rows [row0, row0+32) ----
    int row0 = __builtin_amdgcn_readfirstlane(base + wv*32);
    int n0 = row0 >> 4;
    int   iv_l = idx[row0 + (lane & 31)];
    float a0_l = pr1[(size_t)(row0 + (lane & 31))*3 + 0];
    float a1_l = pr1[(size_t)(row0 + (lane & 31))*3 + 1];
    float a2_l = pr1[(size_t)(row0 + (lane & 31))*3 + 2];
    float xqA = xq[(size_t)(n0+0)*CH + lane];
    float xqB = xq[(size_t)(n0+1)*CH + lane];
#pragma unroll
    for (int g = 0; g < 4; g++){
      float xkv[8];
#pragma unroll
      for (int u = 0; u < 8; u++){
        int iv = __shfl(iv_l, g*8 + u);
        xkv[u] = xk[(size_t)iv*CH + lane];
      }
      float xqv = (g < 2) ? xqA : xqB;
#pragma unroll
      for (int u = 0; u < 8; u++){
        int r = g*8 + u;
        float a0 = __shfl(a0_l, r), a1 = __shfl(a1_l, r), a2 = __shfl(a2_l, r);
        float rb0 = fmaxf(fmaf(a0, sc30, sh30), 0.0f);
        float rb1 = fmaxf(fmaf(a1, sc31, sh31), 0.0f);
        float rb2 = fmaxf(fmaf(a2, sc32, sh32), 0.0f);
        float pr2v = bp + rb0*wpa + rb1*wpb + rb2*wpc;
        float w = xkv[u] - xqv + pr2v;
        lds[wv][r][lane] = fmaxf(fmaf(w, bsc, bsh), 0.0f);
      }
    }
    __syncthreads();
    // ---- phase B: thread handles (row = base+rloc, outputs hf*4..hf*4+3) ----
    {
      float acc0=bb0, acc1=bb1, acc2=bb2, acc3=bb3;
#pragma unroll
      for (int c = 0; c < CH; c += 4){
        float4 rv = *(const float4*)(lrow + c);
        float4 u0 = *(const float4*)(Wr0 + c);
        float4 u1 = *(const float4*)(Wr1 + c);
        float4 u2 = *(const float4*)(Wr2 + c);
        float4 u3 = *(const float4*)(Wr3 + c);
        acc0 += rv.x*u0.x + rv.y*u0.y + rv.z*u0.z + rv.w*u0.w;
        acc1 += rv.x*u1.x + rv.y*u1.y + rv.z*u1.z + rv.w*u1.w;
        acc2 += rv.x*u2.x + rv.y*u2.y + rv.z*u2.z + rv.w*u2.w;
        acc3 += rv.x*u3.x + rv.y*u3.y + rv.z*u3.z + rv.w*u3.w;
      }
      int row = base + rloc;
      float4 st; st.x=acc0; st.y=acc1; st.z=acc2; st.w=acc3;
      *(float4*)(w2o + (size_t)row*8 + hf*4) = st;
      sB0+=acc0; sB1+=acc1; sB2+=acc2; sB3+=acc3;
      qB0+=acc0*acc0; qB1+=acc1*acc1; qB2+=acc2*acc2; qB3+=acc3*acc3;
    }
    __syncthreads();
  }

  // parity-preserving butterfly: sums over lanes of same parity (= same hf)
#pragma unroll
  for (int m = 2; m <= 32; m <<= 1){
    sB0 += __shfl_xor(sB0, m); sB1 += __shfl_xor(sB1, m);
    sB2 += __shfl_xor(sB2, m); sB3 += __shfl_xor(sB3, m);
    qB0 += __shfl_xor(qB0, m); qB1 += __shfl_xor(qB1, m);
    qB2 += __shfl_xor(qB2, m); qB3 += __shfl_xor(qB3, m);
  }
  float* scr = (float*)lds;   // safe: after final __syncthreads of loop
  if (lane < 2){
    scr[wv*16 + lane*4 + 0] = sB0; scr[wv*16 + lane*4 + 1] = sB1;
    scr[wv*16 + lane*4 + 2] = sB2; scr[wv*16 + lane*4 + 3] = sB3;
    scr[wv*16 + 8 + lane*4 + 0] = qB0; scr[wv*16 + 8 + lane*4 + 1] = qB1;
    scr[wv*16 + 8 + lane*4 + 2] = qB2; scr[wv*16 + 8 + lane*4 + 3] = qB3;
  }
  __syncthreads();
  if (t < 16){
    float v = scr[t] + scr[16+t] + scr[32+t] + scr[48+t];
    atomicAdd(s8out + t, v);
  }
}

// final: w3 = relu(bn8(w2)) @ Ww2^T + bw2 ; softmax over 16 neighbors ;
// out = sum_j (xv+p_r2)*w.  All 16 xv gathers issued before softmax.
__global__ __launch_bounds__(256) void k_out(const int* __restrict__ idx,
    const float* __restrict__ xv, const float* __restrict__ pr1,
    const float* __restrict__ w2, const float* __restrict__ f3,
    const float* __restrict__ f8, const float* __restrict__ Wp2,
    const float* __restrict__ bp2, const float* __restrict__ Ww2,
    const float* __restrict__ bw2, float* __restrict__ out)
{
  int lane = threadIdx.x & 63, wv = threadIdx.x >> 6;
  int n = __builtin_amdgcn_readfirstlane(blockIdx.x*4 + wv);
  int cp = lane & 7;
  int jg = lane >> 3;

  // coalesced preload of the point's 16 idx / pr1 rows
  int   iv_l = idx[n*NSAMP + (lane & 15)];
  float a0_l = pr1[(size_t)(n*NSAMP + (lane & 15))*3 + 0];
  float a1_l = pr1[(size_t)(n*NSAMP + (lane & 15))*3 + 1];
  float a2_l = pr1[(size_t)(n*NSAMP + (lane & 15))*3 + 2];

  // issue all 16 xv row-gathers up front (overlap with softmax below)
  float xvv[16];
#pragma unroll
  for (int j = 0; j < 16; j++){
    int iv = __shfl(iv_l, j);
    xvv[j] = xv[(size_t)iv*CH + lane];
  }

  float wpa = Wp2[lane*3+0], wpb = Wp2[lane*3+1], wpc = Wp2[lane*3+2];
  float bp  = bp2[lane];
  float ww2_[8];
#pragma unroll
  for (int k = 0; k < 8; k++) ww2_[k] = Ww2[cp*8 + k];
  float bw = bw2[cp];
  float sc8[8], sh8[8];
#pragma unroll
  for (int k = 0; k < 8; k++){ sc8[k]=f8[k]; sh8[k]=f8[8+k]; }
  float sc30=f3[0], sc31=f3[1], sc32=f3[2], sh30=f3[3], sh31=f3[4], sh32=f3[5];

  // phase 1: w3 for (jg, cp) and (jg+8, cp)
  const float4* ra  = (const float4*)(w2 + ((size_t)n*NSAMP + jg)*8);
  const float4* rbp = (const float4*)(w2 + ((size_t)n*NSAMP + jg + 8)*8);
  float4 A0 = ra[0],  A1 = ra[1];
  float4 B0 = rbp[0], B1 = rbp[1];
  float w3a = bw, w3b = bw;
#pragma unroll
  for (int k = 0; k < 8; k++){
    float va = (k < 4) ? ((k==0)?A0.x:(k==1)?A0.y:(k==2)?A0.z:A0.w)
                       : ((k==4)?A1.x:(k==5)?A1.y:(k==6)?A1.z:A1.w);
    float vb = (k < 4) ? ((k==0)?B0.x:(k==1)?B0.y:(k==2)?B0.z:B0.w)
                       : ((k==4)?B1.x:(k==5)?B1.y:(k==6)?B1.z:B1.w);
    float rba = fmaxf(va*sc8[k]+sh8[k], 0.0f);
    float rbb = fmaxf(vb*sc8[k]+sh8[k], 0.0f);
    w3a += rba * ww2_[k];
    w3b += rbb * ww2_[k];
  }

  // softmax over 16 neighbors (values for fixed cp live at lanes stride-8)
  float m = fmaxf(w3a, w3b);
#pragma unroll
  for (int mask = 8; mask <= 32; mask <<= 1) m = fmaxf(m, __shfl_xor(m, mask));
  float ea = expf(w3a - m), eb = expf(w3b - m);
  float ssum = ea + eb;
#pragma unroll
  for (int mask = 8; mask <= 32; mask <<= 1) ssum += __shfl_xor(ssum, mask);
  float inv = 1.0f / ssum;
  ea *= inv; eb *= inv;

  // phase 2: accumulate out[n, lane]
  float oacc = 0.0f;
#pragma unroll
  for (int j = 0; j < NSAMP; j++){
    float wn = __shfl(j < 8 ? ea : eb, ((j & 7) << 3) | cp);
    float a0 = __shfl(a0_l, j), a1 = __shfl(a1_l, j), a2 = __shfl(a2_l, j);
    float rb0 = fmaxf(fmaf(a0, sc30, sh30), 0.0f);
    float rb1 = fmaxf(fmaf(a1, sc31, sh31), 0.0f);
    float rb2 = fmaxf(fmaf(a2, sc32, sh32), 0.0f);
    float pr2v = bp + rb0*wpa + rb1*wpb + rb2*wpc;
    oacc += (xvv[j] + pr2v) * wn;
  }
  out[(size_t)n*CH + lane] = oacc;
}

extern "C" void kernel_launch(void* const* d_in, const int* in_sizes, int n_in,
                              void* d_out, int out_size, void* d_ws, size_t ws_size,
                              hipStream_t stream)
{
  const float* p    = (const float*)d_in[0];
  const float* x    = (const float*)d_in[1];
  const int*   idx  = (const int*)d_in[2];
  const float* Wq   = (const float*)d_in[3];
  const float* bq   = (const float*)d_in[4];
  const float* Wk   = (const float*)d_in[5];
  const float* bk   = (const float*)d_in[6];
  const float* Wv   = (const float*)d_in[7];
  const float* bv   = (const float*)d_in[8];
  const float* Wp1  = (const float*)d_in[9];
  const float* bp1  = (const float*)d_in[10];
  const float* gp   = (const float*)d_in[11];
  const float* betap= (const float*)d_in[12];
  const float* Wp2  = (const float*)d_in[13];
  const float* bp2  = (const float*)d_in[14];
  const float* gw1  = (const float*)d_in[15];
  const float* betaw1=(const float*)d_in[16];
  const float* Ww1  = (const float*)d_in[17];
  const float* bw1  = (const float*)d_in[18];
  const float* gw2  = (const float*)d_in[19];
  const float* betaw2=(const float*)d_in[20];
  const float* Ww2  = (const float*)d_in[21];
  const float* bw2  = (const float*)d_in[22];
  float* ws  = (float*)d_ws;
  float* out = (float*)d_out;

  k_zero<<<dim3(1), dim3(512), 0, stream>>>(ws);
  k_proj<<<dim3(NPTS/256, 3), dim3(256), 0, stream>>>(x, Wq,bq, Wk,bk, Wv,bv, ws);
  k_pr1<<<dim3(1024), dim3(256), 0, stream>>>(p, idx, Wp1, bp1, ws);
  k_finalize<<<dim3(1), dim3(64), 0, stream>>>(ws+OFF_S3, ws+OFF_F3, gp, betap, 3);
  k_stats64<<<dim3(4096), dim3(256), 0, stream>>>(idx, ws+OFF_XQ, ws+OFF_XK,
      ws+OFF_PR1, ws+OFF_F3, Wp2, bp2, ws+OFF_S64);
  k_finalize<<<dim3(1), dim3(64), 0, stream>>>(ws+OFF_S64, ws+OFF_F64, gw1, betaw1, 64);
  k_w2<<<dim3(2048), dim3(256), 0, stream>>>(idx, ws+OFF_XQ, ws+OFF_XK, ws+OFF_PR1,
      ws+OFF_F3, ws+OFF_F64, Wp2, bp2, Ww1, bw1, ws+OFF_W2, ws+OFF_S8);
  k_finalize<<<dim3(1), dim3(64), 0, stream>>>(ws+OFF_S8, ws+OFF_F8, gw2, betaw2, 8);
  k_out<<<dim3(NPTS/4), dim3(256), 0, stream>>>(idx, ws+OFF_XV, ws+OFF_PR1, ws+OFF_W2,
      ws+OFF_F3, ws+OFF_F8, Wp2, bp2, Ww2, bw2, out);
}

// Round 3
// 547.154 us; speedup vs baseline: 1.0312x; 1.0312x over previous
//
#include <hip/hip_runtime.h>
#include <math.h>

typedef unsigned short ushort_t;
typedef unsigned int uint_t;

#define NPTS 65536
#define NSAMP 16
#define CH 64
#define NROWS (NPTS*NSAMP)
#define BN_EPS 1e-5f

// workspace layout (float offsets)
#define OFF_S3   0            // sum3[3], sq3[3]
#define OFF_F3   8            // scale3[3], shift3[3]
#define OFF_S64  16           // sum64[64] @16, sq64[64] @80
#define OFF_F64  144          // scale64[64] @144, shift64[64] @208
#define OFF_S8   272          // sum8[8], sq8[8]
#define OFF_F8   288          // scale8[8], shift8[8]
#define OFF_XQ   512
#define OFF_XKH  (OFF_XQ + NPTS*CH)            // bf16 xk: NPTS*CH ushorts
#define OFF_XVH  (OFF_XKH + NPTS*CH/2)         // bf16 xv
#define OFF_PR1  (OFF_XVH + NPTS*CH/2)
#define OFF_W2   (OFF_PR1 + (size_t)NROWS*3)

__device__ __forceinline__ float wave_sum(float v){
#pragma unroll
  for (int m = 32; m > 0; m >>= 1) v += __shfl_xor(v, m);
  return v;
}

__device__ __forceinline__ ushort_t f2bf(float f){
  uint_t u = __float_as_uint(f);
  u += 0x7fffu + ((u >> 16) & 1u);   // round-to-nearest-even
  return (ushort_t)(u >> 16);
}
__device__ __forceinline__ float bf2f(ushort_t h){
  return __uint_as_float(((uint_t)h) << 16);
}

__global__ void k_zero(float* __restrict__ ws){
  if (threadIdx.x < 512) ws[threadIdx.x] = 0.0f;
}

// q/k/v projections: thread per point; y=0 -> xq fp32, y=1 -> xk bf16, y=2 -> xv bf16
__global__ __launch_bounds__(256) void k_proj(const float* __restrict__ x,
    const float* __restrict__ W0, const float* __restrict__ b0,
    const float* __restrict__ W1, const float* __restrict__ b1,
    const float* __restrict__ W2, const float* __restrict__ b2,
    float* __restrict__ xqo, ushort_t* __restrict__ xkh, ushort_t* __restrict__ xvh)
{
  int n = blockIdx.x * blockDim.x + threadIdx.x;
  const float* W; const float* b;
  if (blockIdx.y == 0)      { W = W0; b = b0; }
  else if (blockIdx.y == 1) { W = W1; b = b1; }
  else                      { W = W2; b = b2; }

  float4 xr[16];
  const float4* xp = (const float4*)(x + (size_t)n * CH);
#pragma unroll
  for (int i = 0; i < 16; i++) xr[i] = xp[i];

  float4* opf = (float4*)(xqo + (size_t)n * CH);
  ushort_t* oph = ((blockIdx.y == 1) ? xkh : xvh) + (size_t)n * CH;

#pragma unroll 1
  for (int o4 = 0; o4 < 16; o4++){
    float a[4];
#pragma unroll
    for (int oo = 0; oo < 4; oo++){
      int o = o4 * 4 + oo;
      float acc = b[o];
      const float4* wp = (const float4*)(W + o * CH);
#pragma unroll
      for (int i = 0; i < 16; i++){
        float4 w4 = wp[i];
        acc += xr[i].x * w4.x + xr[i].y * w4.y + xr[i].z * w4.z + xr[i].w * w4.w;
      }
      a[oo] = acc;
    }
    if (blockIdx.y == 0){
      float4 st; st.x = a[0]; st.y = a[1]; st.z = a[2]; st.w = a[3];
      opf[o4] = st;
    } else {
      uint2 st;
      st.x = (uint_t)f2bf(a[0]) | ((uint_t)f2bf(a[1]) << 16);
      st.y = (uint_t)f2bf(a[2]) | ((uint_t)f2bf(a[3]) << 16);
      ((uint2*)oph)[o4] = st;
    }
  }
}

// p_r stage 1 (Linear(3,3)) + BN3 partial sums. 4 rows/thread, full ILP.
__global__ __launch_bounds__(256) void k_pr1(const float* __restrict__ p,
    const int* __restrict__ idx, const float* __restrict__ Wp1,
    const float* __restrict__ bp1, float* __restrict__ ws)
{
  float* pr1 = ws + OFF_PR1;
  float w00=Wp1[0],w01=Wp1[1],w02=Wp1[2];
  float w10=Wp1[3],w11=Wp1[4],w12=Wp1[5];
  float w20=Wp1[6],w21=Wp1[7],w22=Wp1[8];
  float b0=bp1[0],b1=bp1[1],b2=bp1[2];
  float s0=0,s1=0,s2=0,q0=0,q1=0,q2=0;
  int r0 = blockIdx.x*256 + threadIdx.x;
#pragma unroll
  for (int it = 0; it < 4; it++){
    int r = r0 + it*262144;
    int n = r >> 4;
    int iv = idx[r];
    float dx = p[iv*3+0] - p[n*3+0];
    float dy = p[iv*3+1] - p[n*3+1];
    float dz = p[iv*3+2] - p[n*3+2];
    float v0 = b0 + dx*w00 + dy*w01 + dz*w02;
    float v1 = b1 + dx*w10 + dy*w11 + dz*w12;
    float v2 = b2 + dx*w20 + dy*w21 + dz*w22;
    pr1[(size_t)r*3+0]=v0; pr1[(size_t)r*3+1]=v1; pr1[(size_t)r*3+2]=v2;
    s0+=v0; s1+=v1; s2+=v2;
    q0+=v0*v0; q1+=v1*v1; q2+=v2*v2;
  }
  s0=wave_sum(s0); s1=wave_sum(s1); s2=wave_sum(s2);
  q0=wave_sum(q0); q1=wave_sum(q1); q2=wave_sum(q2);
  __shared__ float lds[4][6];
  int lane = threadIdx.x & 63, wv = threadIdx.x >> 6;
  if (lane == 0){
    lds[wv][0]=s0; lds[wv][1]=s1; lds[wv][2]=s2;
    lds[wv][3]=q0; lds[wv][4]=q1; lds[wv][5]=q2;
  }
  __syncthreads();
  if (threadIdx.x < 6){
    float v = lds[0][threadIdx.x]+lds[1][threadIdx.x]+lds[2][threadIdx.x]+lds[3][threadIdx.x];
    atomicAdd(ws + OFF_S3 + threadIdx.x, v);
  }
}

// BN finalize: scale = g*rsqrt(var+eps), shift = beta - mean*scale
__global__ void k_finalize(const float* __restrict__ sums, float* __restrict__ outf,
                           const float* __restrict__ g, const float* __restrict__ beta, int nch)
{
  int t = threadIdx.x;
  if (t < nch){
    float invM = 1.0f / (float)NROWS;
    float mean = sums[t] * invM;
    float var  = sums[nch + t] * invM - mean * mean;
    float rs   = rsqrtf(var + BN_EPS);
    float sc   = g[t] * rs;
    outf[t] = sc;
    outf[nch + t] = beta[t] - mean * sc;
  }
}

// BN64 stats over w_pre = xk[idx] - xq + p_r2. Wave per 64-row chunk,
// lane = channel; bf16 xk gathers, 8 in flight.
__global__ __launch_bounds__(256) void k_stats64(const int* __restrict__ idx,
    const float* __restrict__ xq, const ushort_t* __restrict__ xkh,
    const float* __restrict__ pr1, const float* __restrict__ f3,
    const float* __restrict__ Wp2, const float* __restrict__ bp2,
    float* __restrict__ s64)
{
  int lane = threadIdx.x & 63, wv = threadIdx.x >> 6;
  int row0 = __builtin_amdgcn_readfirstlane((blockIdx.x*4 + wv) * 64);
  int n0 = row0 >> 4;

  int   iv_l = idx[row0 + lane];
  float a0_l = pr1[(size_t)(row0 + lane)*3 + 0];
  float a1_l = pr1[(size_t)(row0 + lane)*3 + 1];
  float a2_l = pr1[(size_t)(row0 + lane)*3 + 2];

  float sc0=f3[0], sc1=f3[1], sc2=f3[2], sh0=f3[3], sh1=f3[4], sh2=f3[5];
  float wpa = Wp2[lane*3+0], wpb = Wp2[lane*3+1], wpc = Wp2[lane*3+2];
  float bp  = bp2[lane];

  float xqv0 = xq[(size_t)(n0+0)*CH + lane];
  float xqv1 = xq[(size_t)(n0+1)*CH + lane];
  float xqv2 = xq[(size_t)(n0+2)*CH + lane];
  float xqv3 = xq[(size_t)(n0+3)*CH + lane];

  float accs = 0.0f, accq = 0.0f;
#pragma unroll
  for (int g = 0; g < 8; g++){
    ushort_t xkv[8];
#pragma unroll
    for (int u = 0; u < 8; u++){
      int iv = __shfl(iv_l, g*8 + u);
      xkv[u] = xkh[(size_t)iv*CH + lane];
    }
    float xqv = (g < 2) ? xqv0 : (g < 4) ? xqv1 : (g < 6) ? xqv2 : xqv3;
#pragma unroll
    for (int u = 0; u < 8; u++){
      int r = g*8 + u;
      float a0 = __shfl(a0_l, r), a1 = __shfl(a1_l, r), a2 = __shfl(a2_l, r);
      float rb0 = fmaxf(fmaf(a0, sc0, sh0), 0.0f);
      float rb1 = fmaxf(fmaf(a1, sc1, sh1), 0.0f);
      float rb2 = fmaxf(fmaf(a2, sc2, sh2), 0.0f);
      float pr2v = bp + rb0*wpa + rb1*wpb + rb2*wpc;
      float w = bf2f(xkv[u]) - xqv + pr2v;
      accs += w; accq = fmaf(w, w, accq);
    }
  }
  __shared__ float lds[4][128];
  lds[wv][lane] = accs; lds[wv][64+lane] = accq;
  __syncthreads();
  if (threadIdx.x < 128){
    float v = lds[0][threadIdx.x]+lds[1][threadIdx.x]+lds[2][threadIdx.x]+lds[3][threadIdx.x];
    atomicAdd(s64 + threadIdx.x, v);
  }
}

// w2 = relu(bn64(w_pre)) @ Ww1^T + bw1 + BN8 partial sums.
// Wave-synchronous: wave owns 64 rows; per 8-row tile:
//   phase A (lane=channel): gather xk, compute rb -> wave-private LDS [8][68]
//   phase B (lane=(row u, out o)): 64-FMA dot with per-lane Ww1 row in regs
// No __syncthreads in the main loop; gathers double-buffered.
__global__ __launch_bounds__(256) void k_w2(const int* __restrict__ idx,
    const float* __restrict__ xq, const ushort_t* __restrict__ xkh,
    const float* __restrict__ pr1, const float* __restrict__ f3,
    const float* __restrict__ f64, const float* __restrict__ Wp2,
    const float* __restrict__ bp2, const float* __restrict__ Ww1,
    const float* __restrict__ bw1, float* __restrict__ w2o,
    float* __restrict__ s8out)
{
  __shared__ __align__(16) float lds[4][8][68];
  __shared__ float scr[4][16];
  int lane = threadIdx.x & 63, wv = threadIdx.x >> 6;
  int o = lane & 7, u = lane >> 3;
  int row0 = __builtin_amdgcn_readfirstlane((blockIdx.x*4 + wv) * 64);
  int n0 = row0 >> 4;

  int   iv_l = idx[row0 + lane];
  float a0_l = pr1[(size_t)(row0+lane)*3+0];
  float a1_l = pr1[(size_t)(row0+lane)*3+1];
  float a2_l = pr1[(size_t)(row0+lane)*3+2];

  float sc30=f3[0], sc31=f3[1], sc32=f3[2], sh30=f3[3], sh31=f3[4], sh32=f3[5];
  float wpa = Wp2[lane*3+0], wpb = Wp2[lane*3+1], wpc = Wp2[lane*3+2];
  float bp  = bp2[lane];
  float bsc = f64[lane], bsh = f64[64+lane];

  // per-lane weight row o of Ww1 (8 distinct rows, broadcast across lane groups)
  float Wl[64];
#pragma unroll
  for (int c4 = 0; c4 < 16; c4++){
    float4 w4 = *(const float4*)(Ww1 + o*CH + c4*4);
    Wl[c4*4+0]=w4.x; Wl[c4*4+1]=w4.y; Wl[c4*4+2]=w4.z; Wl[c4*4+3]=w4.w;
  }
  float bb = bw1[o];
  float xqv[4];
#pragma unroll
  for (int j = 0; j < 4; j++) xqv[j] = xq[(size_t)(n0+j)*CH + lane];

  float ssum = 0.0f, qsum = 0.0f;
  ushort_t xkc[8], xkn[8];
#pragma unroll
  for (int t = 0; t < 8; t++) xkc[t] = xkh[(size_t)__shfl(iv_l, t)*CH + lane];

#pragma unroll
  for (int g = 0; g < 8; g++){
    if (g < 7){
#pragma unroll
      for (int t = 0; t < 8; t++)
        xkn[t] = xkh[(size_t)__shfl(iv_l, (g+1)*8 + t)*CH + lane];
    }
    float xqcur = xqv[g >> 1];
    // phase A: rb for 8 rows, lane = channel
#pragma unroll
    for (int t = 0; t < 8; t++){
      int r = g*8 + t;
      float a0 = __shfl(a0_l, r), a1 = __shfl(a1_l, r), a2 = __shfl(a2_l, r);
      float rb0 = fmaxf(fmaf(a0, sc30, sh30), 0.0f);
      float rb1 = fmaxf(fmaf(a1, sc31, sh31), 0.0f);
      float rb2 = fmaxf(fmaf(a2, sc32, sh32), 0.0f);
      float pr2v = bp + rb0*wpa + rb1*wpb + rb2*wpc;
      float w = bf2f(xkc[t]) - xqcur + pr2v;
      lds[wv][t][lane] = fmaxf(fmaf(w, bsc, bsh), 0.0f);
    }
    // phase B: same wave, lane = (u,o). ds_write->ds_read ordered by lgkmcnt.
    float acc = bb;
#pragma unroll
    for (int c4 = 0; c4 < 16; c4++){
      float4 rv = *(const float4*)(&lds[wv][u][c4*4]);
      acc += rv.x*Wl[c4*4+0] + rv.y*Wl[c4*4+1] + rv.z*Wl[c4*4+2] + rv.w*Wl[c4*4+3];
    }
    w2o[(size_t)row0*8 + g*64 + lane] = acc;   // == (row0+g*8+u)*8 + o
    ssum += acc; qsum = fmaf(acc, acc, qsum);
#pragma unroll
    for (int t = 0; t < 8; t++) xkc[t] = xkn[t];
  }

  // per-o reduction: sum over u (lane bits 3..5)
#pragma unroll
  for (int m = 8; m <= 32; m <<= 1){
    ssum += __shfl_xor(ssum, m);
    qsum += __shfl_xor(qsum, m);
  }
  if (lane < 8){ scr[wv][lane] = ssum; scr[wv][8+lane] = qsum; }
  __syncthreads();
  if (threadIdx.x < 16){
    float v = scr[0][threadIdx.x]+scr[1][threadIdx.x]+scr[2][threadIdx.x]+scr[3][threadIdx.x];
    atomicAdd(s8out + threadIdx.x, v);
  }
}

// final: w3 = relu(bn8(w2)) @ Ww2^T + bw2 ; softmax over 16 neighbors ;
// out = sum_j (xv+p_r2)*w.  All 16 bf16 xv gathers issued before softmax.
__global__ __launch_bounds__(256) void k_out(const int* __restrict__ idx,
    const ushort_t* __restrict__ xvh, const float* __restrict__ pr1,
    const float* __restrict__ w2, const float* __restrict__ f3,
    const float* __restrict__ f8, const float* __restrict__ Wp2,
    const float* __restrict__ bp2, const float* __restrict__ Ww2,
    const float* __restrict__ bw2, float* __restrict__ out)
{
  int lane = threadIdx.x & 63, wv = threadIdx.x >> 6;
  int n = __builtin_amdgcn_readfirstlane(blockIdx.x*4 + wv);
  int cp = lane & 7;
  int jg = lane >> 3;

  // coalesced preload of the point's 16 idx / pr1 rows
  int   iv_l = idx[n*NSAMP + (lane & 15)];
  float a0_l = pr1[(size_t)(n*NSAMP + (lane & 15))*3 + 0];
  float a1_l = pr1[(size_t)(n*NSAMP + (lane & 15))*3 + 1];
  float a2_l = pr1[(size_t)(n*NSAMP + (lane & 15))*3 + 2];

  // issue all 16 xv row-gathers up front (overlap with softmax below)
  ushort_t xvv[16];
#pragma unroll
  for (int j = 0; j < 16; j++){
    int iv = __shfl(iv_l, j);
    xvv[j] = xvh[(size_t)iv*CH + lane];
  }

  float wpa = Wp2[lane*3+0], wpb = Wp2[lane*3+1], wpc = Wp2[lane*3+2];
  float bp  = bp2[lane];
  float ww2_[8];
#pragma unroll
  for (int k = 0; k < 8; k++) ww2_[k] = Ww2[cp*8 + k];
  float bw = bw2[cp];
  float sc8[8], sh8[8];
#pragma unroll
  for (int k = 0; k < 8; k++){ sc8[k]=f8[k]; sh8[k]=f8[8+k]; }
  float sc30=f3[0], sc31=f3[1], sc32=f3[2], sh30=f3[3], sh31=f3[4], sh32=f3[5];

  // phase 1: w3 for (jg, cp) and (jg+8, cp)
  const float4* ra  = (const float4*)(w2 + ((size_t)n*NSAMP + jg)*8);
  const float4* rbp = (const float4*)(w2 + ((size_t)n*NSAMP + jg + 8)*8);
  float4 A0 = ra[0],  A1 = ra[1];
  float4 B0 = rbp[0], B1 = rbp[1];
  float w3a = bw, w3b = bw;
#pragma unroll
  for (int k = 0; k < 8; k++){
    float va = (k < 4) ? ((k==0)?A0.x:(k==1)?A0.y:(k==2)?A0.z:A0.w)
                       : ((k==4)?A1.x:(k==5)?A1.y:(k==6)?A1.z:A1.w);
    float vb = (k < 4) ? ((k==0)?B0.x:(k==1)?B0.y:(k==2)?B0.z:B0.w)
                       : ((k==4)?B1.x:(k==5)?B1.y:(k==6)?B1.z:B1.w);
    float rba = fmaxf(va*sc8[k]+sh8[k], 0.0f);
    float rbb = fmaxf(vb*sc8[k]+sh8[k], 0.0f);
    w3a += rba * ww2_[k];
    w3b += rbb * ww2_[k];
  }

  // softmax over 16 neighbors (values for fixed cp live at lanes stride-8)
  float m = fmaxf(w3a, w3b);
#pragma unroll
  for (int mask = 8; mask <= 32; mask <<= 1) m = fmaxf(m, __shfl_xor(m, mask));
  float ea = expf(w3a - m), eb = expf(w3b - m);
  float ssum = ea + eb;
#pragma unroll
  for (int mask = 8; mask <= 32; mask <<= 1) ssum += __shfl_xor(ssum, mask);
  float inv = 1.0f / ssum;
  ea *= inv; eb *= inv;

  // phase 2: accumulate out[n, lane]
  float oacc = 0.0f;
#pragma unroll
  for (int j = 0; j < NSAMP; j++){
    float wn = __shfl(j < 8 ? ea : eb, ((j & 7) << 3) | cp);
    float a0 = __shfl(a0_l, j), a1 = __shfl(a1_l, j), a2 = __shfl(a2_l, j);
    float rb0 = fmaxf(fmaf(a0, sc30, sh30), 0.0f);
    float rb1 = fmaxf(fmaf(a1, sc31, sh31), 0.0f);
    float rb2 = fmaxf(fmaf(a2, sc32, sh32), 0.0f);
    float pr2v = bp + rb0*wpa + rb1*wpb + rb2*wpc;
    oacc += (bf2f(xvv[j]) + pr2v) * wn;
  }
  out[(size_t)n*CH + lane] = oacc;
}

extern "C" void kernel_launch(void* const* d_in, const int* in_sizes, int n_in,
                              void* d_out, int out_size, void* d_ws, size_t ws_size,
                              hipStream_t stream)
{
  const float* p    = (const float*)d_in[0];
  const float* x    = (const float*)d_in[1];
  const int*   idx  = (const int*)d_in[2];
  const float* Wq   = (const float*)d_in[3];
  const float* bq   = (const float*)d_in[4];
  const float* Wk   = (const float*)d_in[5];
  const float* bk   = (const float*)d_in[6];
  const float* Wv   = (const float*)d_in[7];
  const float* bv   = (const float*)d_in[8];
  const float* Wp1  = (const float*)d_in[9];
  const float* bp1  = (const float*)d_in[10];
  const float* gp   = (const float*)d_in[11];
  const float* betap= (const float*)d_in[12];
  const float* Wp2  = (const float*)d_in[13];
  const float* bp2  = (const float*)d_in[14];
  const float* gw1  = (const float*)d_in[15];
  const float* betaw1=(const float*)d_in[16];
  const float* Ww1  = (const float*)d_in[17];
  const float* bw1  = (const float*)d_in[18];
  const float* gw2  = (const float*)d_in[19];
  const float* betaw2=(const float*)d_in[20];
  const float* Ww2  = (const float*)d_in[21];
  const float* bw2  = (const float*)d_in[22];
  float* ws  = (float*)d_ws;
  float* out = (float*)d_out;

  float*    xq  = ws + OFF_XQ;
  ushort_t* xkh = (ushort_t*)(ws + OFF_XKH);
  ushort_t* xvh = (ushort_t*)(ws + OFF_XVH);

  k_zero<<<dim3(1), dim3(512), 0, stream>>>(ws);
  k_proj<<<dim3(NPTS/256, 3), dim3(256), 0, stream>>>(x, Wq,bq, Wk,bk, Wv,bv,
      xq, xkh, xvh);
  k_pr1<<<dim3(1024), dim3(256), 0, stream>>>(p, idx, Wp1, bp1, ws);
  k_finalize<<<dim3(1), dim3(64), 0, stream>>>(ws+OFF_S3, ws+OFF_F3, gp, betap, 3);
  k_stats64<<<dim3(4096), dim3(256), 0, stream>>>(idx, xq, xkh,
      ws+OFF_PR1, ws+OFF_F3, Wp2, bp2, ws+OFF_S64);
  k_finalize<<<dim3(1), dim3(64), 0, stream>>>(ws+OFF_S64, ws+OFF_F64, gw1, betaw1, 64);
  k_w2<<<dim3(4096), dim3(256), 0, stream>>>(idx, xq, xkh, ws+OFF_PR1,
      ws+OFF_F3, ws+OFF_F64, Wp2, bp2, Ww1, bw1, ws+OFF_W2, ws+OFF_S8);
  k_finalize<<<dim3(1), dim3(64), 0, stream>>>(ws+OFF_S8, ws+OFF_F8, gw2, betaw2, 8);
  k_out<<<dim3(NPTS/4), dim3(256), 0, stream>>>(idx, xvh, ws+OFF_PR1, ws+OFF_W2,
      ws+OFF_F3, ws+OFF_F8, Wp2, bp2, Ww2, bw2, out);
}